// Round 6
// baseline (1650.386 us; speedup 1.0000x reference)
//
#include <hip/hip_runtime.h>
#include <hip/hip_bf16.h>
#include <cstddef>

// Problem constants
#define BB 4
#define KK 32      // KMOD
#define TTT 64     // T
#define NNC 128    // N
#define GG4 512    // 4N
// ws layout (floats):
//   X    [4][32][64][128]            = 1048576
//   h    [inst][b][s][256]           = 2097152
//   red2 [4][256][2]                 = 2048     (per-WG GroupNorm partials)
//   pre  [bid][st(scan order)][512]  = 8388608  (plain gate-row indexing)

__device__ __forceinline__ float sigm(float x) { return 1.f / (1.f + __expf(-x)); }
__device__ __forceinline__ float tanh_fast(float x) {
    x = fminf(fmaxf(x, -15.f), 15.f);
    float e = __expf(2.f * x);
    return (e - 1.f) / (e + 1.f);
}

// copy x -> X and emit GroupNorm partials. 1024 blocks x 256 thr, 1 float4/thr.
__global__ void k_copy_red(const float4* __restrict__ src, float4* __restrict__ dst,
                           float* __restrict__ red2) {
    const int i = blockIdx.x * 256 + threadIdx.x;
    const float4 v = src[i];
    dst[i] = v;
    float s  = v.x + v.y + v.z + v.w;
    float ss = v.x * v.x + v.y * v.y + v.z * v.z + v.w * v.w;
    for (int off = 32; off; off >>= 1) {
        s  += __shfl_down(s, off);
        ss += __shfl_down(ss, off);
    }
    __shared__ float l0[4], l1[4];
    const int w = threadIdx.x >> 6;
    if ((threadIdx.x & 63) == 0) { l0[w] = s; l1[w] = ss; }
    __syncthreads();
    if (threadIdx.x == 0) {
        const int b = blockIdx.x >> 8, slot = blockIdx.x & 255;
        red2[(b * 256 + slot) * 2]     = l0[0] + l0[1] + l0[2] + l0[3];
        red2[(b * 256 + slot) * 2 + 1] = l1[0] + l1[1] + l1[2] + l1[3];
    }
}

#define DOT32(WARR, XV4)                                                        \
    {                                                                           \
        _Pragma("unroll")                                                       \
        for (int k = 0; k < 8; ++k) {                                           \
            const float4 h0 = XV4[4 * k];                                       \
            const float4 h1 = XV4[4 * k + 1];                                   \
            const float4 h2 = XV4[4 * k + 2];                                   \
            const float4 h3 = XV4[4 * k + 3];                                   \
            a0 += WARR[4*k].x   * h0.x + WARR[4*k].y   * h0.y                   \
                + WARR[4*k].z   * h0.z + WARR[4*k].w   * h0.w;                  \
            a1 += WARR[4*k+1].x * h1.x + WARR[4*k+1].y * h1.y                   \
                + WARR[4*k+1].z * h1.z + WARR[4*k+1].w * h1.w;                  \
            a2 += WARR[4*k+2].x * h2.x + WARR[4*k+2].y * h2.y                   \
                + WARR[4*k+2].z * h2.z + WARR[4*k+2].w * h2.w;                  \
            a3 += WARR[4*k+3].x * h3.x + WARR[4*k+3].y * h3.y                   \
                + WARR[4*k+3].z * h3.z + WARR[4*k+3].w * h3.w;                  \
        }                                                                       \
    }

// ---------------------------------------------------------------------------
// k_pre4: GroupNorm-apply + input projection. WG per (inst, dir, b); 512 thr.
// Thread g holds the FULL 128-float w_ih row (32 float4 = 128 VGPR). Step loop
// is barrier-free: broadcast xn reads, full dot in registers, coalesced store.
// pre written in SCAN ORDER (dir reversal applied on the xn side).
// ---------------------------------------------------------------------------
template <bool BAND>
__global__ __launch_bounds__(512, 2) void k_pre4(
    const float* __restrict__ X, float* __restrict__ pre,
    const float* __restrict__ red2,
    const float* __restrict__ w_ih,
    const float* __restrict__ b_ih, const float* __restrict__ b_hh,
    const float* __restrict__ gn_g, const float* __restrict__ gn_b,
    int layer)
{
    constexpr int S    = BAND ? 32 : 64;
    constexpr int INST = BAND ? 64 : 32;
    const int g   = threadIdx.x;
    const int bid = blockIdx.x;
    const int b = bid & 3, dir = (bid >> 2) & 1, inst = bid >> 3;

    __shared__ float xn[S * 128];

    // mean / rstd from per-WG partials (uniform address -> scalar loads)
    float s0 = 0.f, s1 = 0.f;
    {
        const float* rp = red2 + b * 512;
#pragma unroll 8
        for (int i = 0; i < 512; i += 2) { s0 += rp[i]; s1 += rp[i + 1]; }
    }
    const float mu = s0 * (1.0f / 262144.0f);
    const float rs = rsqrtf(fmaxf(s1 * (1.0f / 262144.0f) - mu * mu, 0.f) + 1e-5f);

    // normalize this WG's x-slice into LDS
    {
        const size_t xbase = BAND ? ((size_t)b * 2048 + inst) * 128
                                  : ((size_t)b * 32 + inst) * 64 * 128;
        const float* gmg = gn_g + layer * 128;
        const float* gmb = gn_b + layer * 128;
        for (int i4 = g; i4 < S * 32; i4 += 512) {
            int srow = i4 >> 5, n4 = i4 & 31;
            const float4 v = *(const float4*)(X + xbase +
                              (BAND ? (size_t)srow * 8192 : (size_t)srow * 128) + n4 * 4);
            const float4 ga = *(const float4*)(gmg + n4 * 4);
            const float4 be = *(const float4*)(gmb + n4 * 4);
            float4 o;
            o.x = (v.x - mu) * rs * ga.x + be.x;
            o.y = (v.y - mu) * rs * ga.y + be.y;
            o.z = (v.z - mu) * rs * ga.z + be.z;
            o.w = (v.w - mu) * rs * ga.w + be.w;
            *(float4*)(xn + srow * 128 + n4 * 4) = o;
        }
    }

    // full row of w_ih: 32 float4 (128 VGPR), statically indexed
    const size_t wbase = ((size_t)layer * INST + inst) * 2 + dir;
    float4 w4[32];
    {
        const float* wr = w_ih + (wbase * 512 + g) * 128;
#pragma unroll
        for (int k = 0; k < 32; ++k) w4[k] = *(const float4*)(wr + 4 * k);
    }
    const float bias = b_ih[wbase * 512 + g] + b_hh[wbase * 512 + g];
    __syncthreads();

    float* pb = pre + (size_t)bid * (S * 512) + g;
    for (int st = 0; st < S; ++st) {
        const int sidx = dir ? (S - 1 - st) : st;
        const float4* xr = (const float4*)(xn + sidx * 128);   // broadcast reads
        float a0 = bias, a1 = 0.f, a2 = 0.f, a3 = 0.f;
        DOT32(w4, xr)
        pb[(size_t)st * 512] = (a0 + a1) + (a2 + a3);          // coalesced
    }
}

// ---------------------------------------------------------------------------
// k_scan4: recurrence. WG per (inst, dir, b); 512 thr; thread g holds the FULL
// 128-float w_hh row (32 float4). Per step: 32 broadcast ds_read_b128 + 128 FMA
// (no cross-lane reduce), pre streamed from global with register prefetch,
// activation (wave-uniform gate select) -> gbuf -> combine by g<128 -> barrier.
// ---------------------------------------------------------------------------
template <bool BAND>
__global__ __launch_bounds__(512, 2) void k_scan4(
    const float* __restrict__ pre, float* __restrict__ hout,
    const float* __restrict__ w_hh, int layer)
{
    constexpr int S    = BAND ? 32 : 64;
    constexpr int INST = BAND ? 64 : 32;
    const int g   = threadIdx.x;
    const int bid = blockIdx.x;
    const int b = bid & 3, dir = (bid >> 2) & 1, inst = bid >> 3;

    __shared__ float gbuf[512];
    __shared__ float hbuf[2][128];

    const size_t wbase = ((size_t)layer * INST + inst) * 2 + dir;
    float4 w4[32];
    {
        const float* wr = w_hh + (wbase * 512 + g) * 128;
#pragma unroll
        for (int k = 0; k < 32; ++k) w4[k] = *(const float4*)(wr + 4 * k);
    }

    const float* pb = pre + (size_t)bid * (S * 512) + g;
    float pcur = pb[0];
    if (g < 128) { hbuf[0][g] = 0.f; hbuf[1][g] = 0.f; }
    float c = 0.f;
    __syncthreads();

    float* hob = hout + (((size_t)inst * 4 + b) * S) * 256 + dir * 128;
    int cur = 0;

    for (int st = 0; st < S; ++st) {
        const float pnext = (st + 1 < S) ? pb[(size_t)(st + 1) * 512] : 0.f;
        const float4* hv4 = (const float4*)hbuf[cur];          // broadcast reads
        float a0 = pcur, a1 = 0.f, a2 = 0.f, a3 = 0.f;
        DOT32(w4, hv4)
        const float dot = (a0 + a1) + (a2 + a3);
        // gate blocks of 128 rows align with 64-lane waves -> uniform branch
        const float act = ((g >> 7) == 2) ? tanh_fast(dot) : sigm(dot);
        gbuf[g] = act;
        __syncthreads();
        if (g < 128) {
            const float gi = gbuf[g];
            const float gf = gbuf[g + 128];
            const float gG = gbuf[g + 256];
            const float go = gbuf[g + 384];
            c = gf * c + gi * gG;
            const float hval = go * tanh_fast(c);
            hbuf[cur ^ 1][g] = hval;
            const int sidx = dir ? (S - 1 - st) : st;
            hob[(size_t)sidx * 256 + g] = hval;
        }
        __syncthreads();
        pcur = pnext;
        cur ^= 1;
    }
}

// FC (h[2N] -> N) + bias + residual into X; emits next module's GroupNorm
// partials; final module also writes the sliced output. 1024 WGs x 256 thr.
template <bool BAND>
__global__ void k_fc(const float* __restrict__ h, const float* __restrict__ fc_w,
                     const float* __restrict__ fc_b, float* __restrict__ X,
                     float* __restrict__ red2, float* __restrict__ out,
                     int layer, int final_out)
{
    constexpr int S    = BAND ? 32 : 64;
    constexpr int INST = BAND ? 64 : 32;
    constexpr int RPB  = 8;                       // rows per block
    constexpr int CPB  = S / RPB;                 // chunks per batch
    const int inst  = blockIdx.x / (BB * CPB);
    const int chunk = blockIdx.x % (BB * CPB);

    __shared__ float hs[RPB * 256];
    const int tid = threadIdx.x;
    const float* hbase = h + ((size_t)inst * BB * S + chunk * RPB) * 256;
    for (int i = tid; i < RPB * 64; i += 256)
        ((float4*)hs)[i] = ((const float4*)hbase)[i];
    __syncthreads();

    const int n  = tid & 127;
    const int rg = tid >> 7;                      // 0..1 -> rows rg*4 .. rg*4+3
    const float* wrow = fc_w + (((size_t)layer * INST + inst) * 128 + n) * 256;
    float4 a0 = {0,0,0,0}, a1 = {0,0,0,0}, a2 = {0,0,0,0}, a3 = {0,0,0,0};
#pragma unroll 8
    for (int d4 = 0; d4 < 64; ++d4) {
        float4 wv = ((const float4*)wrow)[d4];
        float4 h0 = ((const float4*)(hs + (rg * 4 + 0) * 256))[d4];
        float4 h1 = ((const float4*)(hs + (rg * 4 + 1) * 256))[d4];
        float4 h2 = ((const float4*)(hs + (rg * 4 + 2) * 256))[d4];
        float4 h3 = ((const float4*)(hs + (rg * 4 + 3) * 256))[d4];
        a0.x += wv.x*h0.x; a0.y += wv.y*h0.y; a0.z += wv.z*h0.z; a0.w += wv.w*h0.w;
        a1.x += wv.x*h1.x; a1.y += wv.y*h1.y; a1.z += wv.z*h1.z; a1.w += wv.w*h1.w;
        a2.x += wv.x*h2.x; a2.y += wv.y*h2.y; a2.z += wv.z*h2.z; a2.w += wv.w*h2.w;
        a3.x += wv.x*h3.x; a3.y += wv.y*h3.y; a3.z += wv.z*h3.z; a3.w += wv.w*h3.w;
    }
    const float bias = fc_b[((size_t)layer * INST + inst) * 128 + n];
    float acc[4];
    acc[0] = (a0.x + a0.y) + (a0.z + a0.w);
    acc[1] = (a1.x + a1.y) + (a1.z + a1.w);
    acc[2] = (a2.x + a2.y) + (a2.z + a2.w);
    acc[3] = (a3.x + a3.y) + (a3.z + a3.w);

    float s = 0.f, ss = 0.f;
#pragma unroll
    for (int i = 0; i < 4; ++i) {
        const int r = chunk * RPB + rg * 4 + i;
        const int b = r / S, sd = r % S;
        const size_t xi = BAND ? (((size_t)b * 32 + sd) * 64 + inst) * 128 + n
                               : (((size_t)b * 32 + inst) * 64 + sd) * 128 + n;
        const float v = X[xi] + acc[i] + bias;
        X[xi] = v;
        s += v; ss += v * v;
        if (BAND && final_out && sd < 30)
            out[(((size_t)b * 30 + sd) * 64 + inst) * 128 + n] = v;
    }
    // per-WG GroupNorm partials for the next module
    for (int off = 32; off; off >>= 1) {
        s  += __shfl_down(s, off);
        ss += __shfl_down(ss, off);
    }
    __shared__ float l0[4], l1[4];
    const int w = tid >> 6;
    if ((tid & 63) == 0) { l0[w] = s; l1[w] = ss; }
    __syncthreads();
    if (tid == 0) {
        const int bsel = chunk / CPB;
        const int slot = inst * CPB + (chunk % CPB);
        red2[(bsel * 256 + slot) * 2]     = l0[0] + l0[1] + l0[2] + l0[3];
        red2[(bsel * 256 + slot) * 2 + 1] = l1[0] + l1[1] + l1[2] + l1[3];
    }
}

extern "C" void kernel_launch(void* const* d_in, const int* in_sizes, int n_in,
                              void* d_out, int out_size, void* d_ws, size_t ws_size,
                              hipStream_t stream) {
    const float* x     = (const float*)d_in[0];
    const float* tw_ih = (const float*)d_in[1];
    const float* tw_hh = (const float*)d_in[2];
    const float* tb_ih = (const float*)d_in[3];
    const float* tb_hh = (const float*)d_in[4];
    const float* tfc_w = (const float*)d_in[5];
    const float* tfc_b = (const float*)d_in[6];
    const float* tgn_g = (const float*)d_in[7];
    const float* tgn_b = (const float*)d_in[8];
    const float* bw_ih = (const float*)d_in[9];
    const float* bw_hh = (const float*)d_in[10];
    const float* bb_ih = (const float*)d_in[11];
    const float* bb_hh = (const float*)d_in[12];
    const float* bfc_w = (const float*)d_in[13];
    const float* bfc_b = (const float*)d_in[14];
    const float* bgn_g = (const float*)d_in[15];
    const float* bgn_b = (const float*)d_in[16];

    float* X    = (float*)d_ws;                // 1048576 floats
    float* h    = X + 1048576;                 // 2097152 floats
    float* red2 = h + 2097152;                 // 2048 floats
    float* pre  = red2 + 2048;                 // 8388608 floats
    float* out  = (float*)d_out;

    k_copy_red<<<1024, 256, 0, stream>>>((const float4*)x, (float4*)X, red2);

    for (int layer = 0; layer < 2; ++layer) {
        // temporal module (per-band LSTM over T)
        k_pre4<false><<<256, 512, 0, stream>>>(X, pre, red2, tw_ih, tb_ih, tb_hh,
                                               tgn_g, tgn_b, layer);
        k_scan4<false><<<256, 512, 0, stream>>>(pre, h, tw_hh, layer);
        k_fc<false><<<1024, 256, 0, stream>>>(h, tfc_w, tfc_b, X, red2, out, layer, 0);
        // band module (per-frame LSTM over K)
        k_pre4<true><<<512, 512, 0, stream>>>(X, pre, red2, bw_ih, bb_ih, bb_hh,
                                              bgn_g, bgn_b, layer);
        k_scan4<true><<<512, 512, 0, stream>>>(pre, h, bw_hh, layer);
        k_fc<true><<<1024, 256, 0, stream>>>(h, bfc_w, bfc_b, X, red2, out,
                                             layer, layer == 1 ? 1 : 0);
    }
}

// Round 14
// 1635.583 us; speedup vs baseline: 1.0091x; 1.0091x over previous
//
#include <hip/hip_runtime.h>
#include <hip/hip_bf16.h>
#include <cstddef>

// Problem constants
#define BB 4
#define KK 32      // KMOD
#define TTT 64     // T
#define NNC 128    // N
#define GG4 512    // 4N
// ws layout (floats):
//   X    [4][32][64][128]            = 1048576
//   h    [inst][b][s][256]           = 2097152
//   red2 [4][256][2]                 = 2048     (per-WG GroupNorm partials)
//   pre  [bid][st(scan order)][512]  = 8388608  (plain gate-row indexing)

__device__ __forceinline__ float sigm(float x) { return 1.f / (1.f + __expf(-x)); }
__device__ __forceinline__ float tanh_fast(float x) {
    x = fminf(fmaxf(x, -15.f), 15.f);
    float e = __expf(2.f * x);
    return (e - 1.f) / (e + 1.f);
}

// copy x -> X and emit GroupNorm partials. 1024 blocks x 256 thr, 1 float4/thr.
__global__ void k_copy_red(const float4* __restrict__ src, float4* __restrict__ dst,
                           float* __restrict__ red2) {
    const int i = blockIdx.x * 256 + threadIdx.x;
    const float4 v = src[i];
    dst[i] = v;
    float s  = v.x + v.y + v.z + v.w;
    float ss = v.x * v.x + v.y * v.y + v.z * v.z + v.w * v.w;
    for (int off = 32; off; off >>= 1) {
        s  += __shfl_down(s, off);
        ss += __shfl_down(ss, off);
    }
    __shared__ float l0[4], l1[4];
    const int w = threadIdx.x >> 6;
    if ((threadIdx.x & 63) == 0) { l0[w] = s; l1[w] = ss; }
    __syncthreads();
    if (threadIdx.x == 0) {
        const int b = blockIdx.x >> 8, slot = blockIdx.x & 255;
        red2[(b * 256 + slot) * 2]     = l0[0] + l0[1] + l0[2] + l0[3];
        red2[(b * 256 + slot) * 2 + 1] = l1[0] + l1[1] + l1[2] + l1[3];
    }
}

#define DOT32(WARR, XV4)                                                        \
    {                                                                           \
        _Pragma("unroll")                                                       \
        for (int k = 0; k < 8; ++k) {                                           \
            const float4 h0 = XV4[4 * k];                                       \
            const float4 h1 = XV4[4 * k + 1];                                   \
            const float4 h2 = XV4[4 * k + 2];                                   \
            const float4 h3 = XV4[4 * k + 3];                                   \
            a0 += WARR[4*k].x   * h0.x + WARR[4*k].y   * h0.y                   \
                + WARR[4*k].z   * h0.z + WARR[4*k].w   * h0.w;                  \
            a1 += WARR[4*k+1].x * h1.x + WARR[4*k+1].y * h1.y                   \
                + WARR[4*k+1].z * h1.z + WARR[4*k+1].w * h1.w;                  \
            a2 += WARR[4*k+2].x * h2.x + WARR[4*k+2].y * h2.y                   \
                + WARR[4*k+2].z * h2.z + WARR[4*k+2].w * h2.w;                  \
            a3 += WARR[4*k+3].x * h3.x + WARR[4*k+3].y * h3.y                   \
                + WARR[4*k+3].z * h3.z + WARR[4*k+3].w * h3.w;                  \
        }                                                                       \
    }

// ---------------------------------------------------------------------------
// k_pre4: GroupNorm-apply + input projection. WG per (inst, dir, b); 512 thr.
// Thread g holds the FULL 128-float w_ih row (32 float4 = 128 VGPR). Step loop
// is barrier-free: broadcast xn reads, full dot in registers, coalesced store.
// pre written in SCAN ORDER (dir reversal applied on the xn side).
// __launch_bounds__(512,1): spill-safe under BOTH semantics (min-waves/EU ->
// 512-VGPR cap; min-blocks/CU -> 256-VGPR cap). Round-6's (512,2) forced a
// 128-VGPR cap -> 150 MB scratch traffic, VALUBusy 15%.
// ---------------------------------------------------------------------------
template <bool BAND>
__global__ __launch_bounds__(512, 1) void k_pre4(
    const float* __restrict__ X, float* __restrict__ pre,
    const float* __restrict__ red2,
    const float* __restrict__ w_ih,
    const float* __restrict__ b_ih, const float* __restrict__ b_hh,
    const float* __restrict__ gn_g, const float* __restrict__ gn_b,
    int layer)
{
    constexpr int S    = BAND ? 32 : 64;
    constexpr int INST = BAND ? 64 : 32;
    const int g   = threadIdx.x;
    const int bid = blockIdx.x;
    const int b = bid & 3, dir = (bid >> 2) & 1, inst = bid >> 3;

    __shared__ float xn[S * 128];

    // mean / rstd from per-WG partials (uniform address -> scalar loads)
    float s0 = 0.f, s1 = 0.f;
    {
        const float* rp = red2 + b * 512;
#pragma unroll 8
        for (int i = 0; i < 512; i += 2) { s0 += rp[i]; s1 += rp[i + 1]; }
    }
    const float mu = s0 * (1.0f / 262144.0f);
    const float rs = rsqrtf(fmaxf(s1 * (1.0f / 262144.0f) - mu * mu, 0.f) + 1e-5f);

    // normalize this WG's x-slice into LDS
    {
        const size_t xbase = BAND ? ((size_t)b * 2048 + inst) * 128
                                  : ((size_t)b * 32 + inst) * 64 * 128;
        const float* gmg = gn_g + layer * 128;
        const float* gmb = gn_b + layer * 128;
        for (int i4 = g; i4 < S * 32; i4 += 512) {
            int srow = i4 >> 5, n4 = i4 & 31;
            const float4 v = *(const float4*)(X + xbase +
                              (BAND ? (size_t)srow * 8192 : (size_t)srow * 128) + n4 * 4);
            const float4 ga = *(const float4*)(gmg + n4 * 4);
            const float4 be = *(const float4*)(gmb + n4 * 4);
            float4 o;
            o.x = (v.x - mu) * rs * ga.x + be.x;
            o.y = (v.y - mu) * rs * ga.y + be.y;
            o.z = (v.z - mu) * rs * ga.z + be.z;
            o.w = (v.w - mu) * rs * ga.w + be.w;
            *(float4*)(xn + srow * 128 + n4 * 4) = o;
        }
    }

    // full row of w_ih: 32 float4 (128 VGPR), statically indexed
    const size_t wbase = ((size_t)layer * INST + inst) * 2 + dir;
    float4 w4[32];
    {
        const float* wr = w_ih + (wbase * 512 + g) * 128;
#pragma unroll
        for (int k = 0; k < 32; ++k) w4[k] = *(const float4*)(wr + 4 * k);
    }
    const float bias = b_ih[wbase * 512 + g] + b_hh[wbase * 512 + g];
    __syncthreads();

    float* pb = pre + (size_t)bid * (S * 512) + g;
    for (int st = 0; st < S; ++st) {
        const int sidx = dir ? (S - 1 - st) : st;
        const float4* xr = (const float4*)(xn + sidx * 128);   // broadcast reads
        float a0 = bias, a1 = 0.f, a2 = 0.f, a3 = 0.f;
        DOT32(w4, xr)
        pb[(size_t)st * 512] = (a0 + a1) + (a2 + a3);          // coalesced
    }
}

// ---------------------------------------------------------------------------
// k_scan4: recurrence. WG per (inst, dir, b); 512 thr; thread g holds the FULL
// 128-float w_hh row (32 float4). Per step: 32 broadcast ds_read_b128 + 128 FMA
// (no cross-lane reduce), pre streamed from global with register prefetch,
// activation (wave-uniform gate select) -> gbuf -> combine by g<128 -> barrier.
// __launch_bounds__(512,1): see k_pre4 note — avoids the 128-VGPR spill cap.
// ---------------------------------------------------------------------------
template <bool BAND>
__global__ __launch_bounds__(512, 1) void k_scan4(
    const float* __restrict__ pre, float* __restrict__ hout,
    const float* __restrict__ w_hh, int layer)
{
    constexpr int S    = BAND ? 32 : 64;
    constexpr int INST = BAND ? 64 : 32;
    const int g   = threadIdx.x;
    const int bid = blockIdx.x;
    const int b = bid & 3, dir = (bid >> 2) & 1, inst = bid >> 3;

    __shared__ float gbuf[512];
    __shared__ float hbuf[2][128];

    const size_t wbase = ((size_t)layer * INST + inst) * 2 + dir;
    float4 w4[32];
    {
        const float* wr = w_hh + (wbase * 512 + g) * 128;
#pragma unroll
        for (int k = 0; k < 32; ++k) w4[k] = *(const float4*)(wr + 4 * k);
    }

    const float* pb = pre + (size_t)bid * (S * 512) + g;
    float pcur = pb[0];
    if (g < 128) { hbuf[0][g] = 0.f; hbuf[1][g] = 0.f; }
    float c = 0.f;
    __syncthreads();

    float* hob = hout + (((size_t)inst * 4 + b) * S) * 256 + dir * 128;
    int cur = 0;

    for (int st = 0; st < S; ++st) {
        const float pnext = (st + 1 < S) ? pb[(size_t)(st + 1) * 512] : 0.f;
        const float4* hv4 = (const float4*)hbuf[cur];          // broadcast reads
        float a0 = pcur, a1 = 0.f, a2 = 0.f, a3 = 0.f;
        DOT32(w4, hv4)
        const float dot = (a0 + a1) + (a2 + a3);
        // gate blocks of 128 rows align with 64-lane waves -> uniform branch
        const float act = ((g >> 7) == 2) ? tanh_fast(dot) : sigm(dot);
        gbuf[g] = act;
        __syncthreads();
        if (g < 128) {
            const float gi = gbuf[g];
            const float gf = gbuf[g + 128];
            const float gG = gbuf[g + 256];
            const float go = gbuf[g + 384];
            c = gf * c + gi * gG;
            const float hval = go * tanh_fast(c);
            hbuf[cur ^ 1][g] = hval;
            const int sidx = dir ? (S - 1 - st) : st;
            hob[(size_t)sidx * 256 + g] = hval;
        }
        __syncthreads();
        pcur = pnext;
        cur ^= 1;
    }
}

// FC (h[2N] -> N) + bias + residual into X; emits next module's GroupNorm
// partials; final module also writes the sliced output. 1024 WGs x 256 thr.
template <bool BAND>
__global__ void k_fc(const float* __restrict__ h, const float* __restrict__ fc_w,
                     const float* __restrict__ fc_b, float* __restrict__ X,
                     float* __restrict__ red2, float* __restrict__ out,
                     int layer, int final_out)
{
    constexpr int S    = BAND ? 32 : 64;
    constexpr int INST = BAND ? 64 : 32;
    constexpr int RPB  = 8;                       // rows per block
    constexpr int CPB  = S / RPB;                 // chunks per batch
    const int inst  = blockIdx.x / (BB * CPB);
    const int chunk = blockIdx.x % (BB * CPB);

    __shared__ float hs[RPB * 256];
    const int tid = threadIdx.x;
    const float* hbase = h + ((size_t)inst * BB * S + chunk * RPB) * 256;
    for (int i = tid; i < RPB * 64; i += 256)
        ((float4*)hs)[i] = ((const float4*)hbase)[i];
    __syncthreads();

    const int n  = tid & 127;
    const int rg = tid >> 7;                      // 0..1 -> rows rg*4 .. rg*4+3
    const float* wrow = fc_w + (((size_t)layer * INST + inst) * 128 + n) * 256;
    float4 a0 = {0,0,0,0}, a1 = {0,0,0,0}, a2 = {0,0,0,0}, a3 = {0,0,0,0};
#pragma unroll 8
    for (int d4 = 0; d4 < 64; ++d4) {
        float4 wv = ((const float4*)wrow)[d4];
        float4 h0 = ((const float4*)(hs + (rg * 4 + 0) * 256))[d4];
        float4 h1 = ((const float4*)(hs + (rg * 4 + 1) * 256))[d4];
        float4 h2 = ((const float4*)(hs + (rg * 4 + 2) * 256))[d4];
        float4 h3 = ((const float4*)(hs + (rg * 4 + 3) * 256))[d4];
        a0.x += wv.x*h0.x; a0.y += wv.y*h0.y; a0.z += wv.z*h0.z; a0.w += wv.w*h0.w;
        a1.x += wv.x*h1.x; a1.y += wv.y*h1.y; a1.z += wv.z*h1.z; a1.w += wv.w*h1.w;
        a2.x += wv.x*h2.x; a2.y += wv.y*h2.y; a2.z += wv.z*h2.z; a2.w += wv.w*h2.w;
        a3.x += wv.x*h3.x; a3.y += wv.y*h3.y; a3.z += wv.z*h3.z; a3.w += wv.w*h3.w;
    }
    const float bias = fc_b[((size_t)layer * INST + inst) * 128 + n];
    float acc[4];
    acc[0] = (a0.x + a0.y) + (a0.z + a0.w);
    acc[1] = (a1.x + a1.y) + (a1.z + a1.w);
    acc[2] = (a2.x + a2.y) + (a2.z + a2.w);
    acc[3] = (a3.x + a3.y) + (a3.z + a3.w);

    float s = 0.f, ss = 0.f;
#pragma unroll
    for (int i = 0; i < 4; ++i) {
        const int r = chunk * RPB + rg * 4 + i;
        const int b = r / S, sd = r % S;
        const size_t xi = BAND ? (((size_t)b * 32 + sd) * 64 + inst) * 128 + n
                               : (((size_t)b * 32 + inst) * 64 + sd) * 128 + n;
        const float v = X[xi] + acc[i] + bias;
        X[xi] = v;
        s += v; ss += v * v;
        if (BAND && final_out && sd < 30)
            out[(((size_t)b * 30 + sd) * 64 + inst) * 128 + n] = v;
    }
    // per-WG GroupNorm partials for the next module
    for (int off = 32; off; off >>= 1) {
        s  += __shfl_down(s, off);
        ss += __shfl_down(ss, off);
    }
    __shared__ float l0[4], l1[4];
    const int w = tid >> 6;
    if ((tid & 63) == 0) { l0[w] = s; l1[w] = ss; }
    __syncthreads();
    if (tid == 0) {
        const int bsel = chunk / CPB;
        const int slot = inst * CPB + (chunk % CPB);
        red2[(bsel * 256 + slot) * 2]     = l0[0] + l0[1] + l0[2] + l0[3];
        red2[(bsel * 256 + slot) * 2 + 1] = l1[0] + l1[1] + l1[2] + l1[3];
    }
}

extern "C" void kernel_launch(void* const* d_in, const int* in_sizes, int n_in,
                              void* d_out, int out_size, void* d_ws, size_t ws_size,
                              hipStream_t stream) {
    const float* x     = (const float*)d_in[0];
    const float* tw_ih = (const float*)d_in[1];
    const float* tw_hh = (const float*)d_in[2];
    const float* tb_ih = (const float*)d_in[3];
    const float* tb_hh = (const float*)d_in[4];
    const float* tfc_w = (const float*)d_in[5];
    const float* tfc_b = (const float*)d_in[6];
    const float* tgn_g = (const float*)d_in[7];
    const float* tgn_b = (const float*)d_in[8];
    const float* bw_ih = (const float*)d_in[9];
    const float* bw_hh = (const float*)d_in[10];
    const float* bb_ih = (const float*)d_in[11];
    const float* bb_hh = (const float*)d_in[12];
    const float* bfc_w = (const float*)d_in[13];
    const float* bfc_b = (const float*)d_in[14];
    const float* bgn_g = (const float*)d_in[15];
    const float* bgn_b = (const float*)d_in[16];

    float* X    = (float*)d_ws;                // 1048576 floats
    float* h    = X + 1048576;                 // 2097152 floats
    float* red2 = h + 2097152;                 // 2048 floats
    float* pre  = red2 + 2048;                 // 8388608 floats
    float* out  = (float*)d_out;

    k_copy_red<<<1024, 256, 0, stream>>>((const float4*)x, (float4*)X, red2);

    for (int layer = 0; layer < 2; ++layer) {
        // temporal module (per-band LSTM over T)
        k_pre4<false><<<256, 512, 0, stream>>>(X, pre, red2, tw_ih, tb_ih, tb_hh,
                                               tgn_g, tgn_b, layer);
        k_scan4<false><<<256, 512, 0, stream>>>(pre, h, tw_hh, layer);
        k_fc<false><<<1024, 256, 0, stream>>>(h, tfc_w, tfc_b, X, red2, out, layer, 0);
        // band module (per-frame LSTM over K)
        k_pre4<true><<<512, 512, 0, stream>>>(X, pre, red2, bw_ih, bb_ih, bb_hh,
                                              bgn_g, bgn_b, layer);
        k_scan4<true><<<512, 512, 0, stream>>>(pre, h, bw_hh, layer);
        k_fc<true><<<1024, 256, 0, stream>>>(h, bfc_w, bfc_b, X, red2, out,
                                             layer, layer == 1 ? 1 : 0);
    }
}